// Round 8
// baseline (1722.429 us; speedup 1.0000x reference)
//
#include <hip/hip_runtime.h>
#include <hip/hip_bf16.h>

// ---------------------------------------------------------------------------
// Treatformer, round 8: MFMA-GEMM-ified treat path.
// ESTABLISHED: inputs fp32 (runtime-probed), output fp32, mask int32,
// pipeline verified (r7: 1595 us, absmax 0.0156).
// r7 rocprof: treat_kernel 413 us (top dispatch), MfmaUtil 0, LDS-bound.
// This round: treat as per-i MFMA GEMM: add[n,i,:] = mask[n,i,:] @ Ewin^T,
// M=32 K=512 N=512, E-window staged transposed to LDS per k-step (bf16),
// A-frags from precomputed bf16 mask (aligned), fp32 acc, t1/t2 in epilogue.
// 17.2 GFLOP -> ~8 us MFMA + ~30 us staging vs 413 us VALU version.
// Spike decode: round(absmax/262144) = bits {18:ff,19:E1,20:dtype-bf16,
// 23:src2,24:h,25:host sizes,26:ws too small}.
// ---------------------------------------------------------------------------

typedef __hip_bfloat16 bf16;
typedef short s8v __attribute__((ext_vector_type(8)));   // 8 bf16 (4 VGPR)
typedef float f4v __attribute__((ext_vector_type(4)));   // MFMA C/D frag

#define T_ 512
#define N_ 32
#define D_ 512
#define H_ 8
#define DH_ 64
#define FF_ 2048
#define MH_ 50
#define EPS_ 1e-5f

__device__ __forceinline__ float tofl(float x) { return x; }
__device__ __forceinline__ float tofl(bf16 x) { return __bfloat162float(x); }

__device__ __forceinline__ void load4(const float* p, float* d) {
    const float4 v = *reinterpret_cast<const float4*>(p);
    d[0] = v.x; d[1] = v.y; d[2] = v.z; d[3] = v.w;
}
__device__ __forceinline__ void load4(const bf16* p, float* d) {
    union { unsigned long long u; unsigned short s[4]; } w;
    w.u = *reinterpret_cast<const unsigned long long*>(p);
#pragma unroll
    for (int i = 0; i < 4; i++) d[i] = __uint_as_float(((unsigned int)w.s[i]) << 16);
}

__device__ __forceinline__ void storeC(float* p, float v) { *p = v; }
__device__ __forceinline__ void storeC(bf16* p, float v) { *p = __float2bfloat16(v); }

// ---------------------------------------------------------------------------
__global__ void probe_kernel(const unsigned short* __restrict__ s,
                             const unsigned char* __restrict__ m,
                             int* __restrict__ flags)
{
    __shared__ int sh[3];
    const int tid = threadIdx.x;
    if (tid < 16) flags[tid] = 0;
    if (tid < 3) sh[tid] = 0;
    __syncthreads();
    int big = 0, zero = 0, nz = 0;
    for (int i = tid; i < 4096; i += 256) {
        const unsigned short h = s[2 * i];
        const unsigned int e = (h >> 7) & 0xff;
        if (e >= 134) big++;
        if ((h & 0x7fff) == 0) zero++;
    }
    for (int i = tid; i < 4096; i += 256)
        if ((i & 3) && m[i]) nz++;
    atomicAdd(&sh[0], big);
    atomicAdd(&sh[1], zero);
    atomicAdd(&sh[2], nz);
    __syncthreads();
    if (tid == 0) {
        flags[0] = (sh[0] > 200 || sh[1] > 2000) ? 1 : 0;  // 1 => fp32 inputs
        flags[1] = (sh[2] == 0) ? 1 : 0;                   // 1 => mask int32
    }
}

struct CvtDesc {
    const void* in[24];
    float* out[24];
    int n[24];
    int cnt;
};
__global__ __launch_bounds__(256) void cvt_kernel(CvtDesc d, const int* __restrict__ flags)
{
    const int fp32 = flags[0];
    const int seg = blockIdx.y;
    if (seg >= d.cnt) return;
    const long n = d.n[seg];
    const void* in = d.in[seg];
    float* out = d.out[seg];
    for (long i = (long)blockIdx.x * 256 + threadIdx.x; i < n; i += (long)gridDim.x * 256) {
        out[i] = fp32 ? ((const float*)in)[i]
                      : __bfloat162float(((const bf16*)in)[i]);
    }
}

struct CvtBfDesc {
    const void* in[8];
    bf16* out[8];
    int n[8];
    int cnt;
};
__global__ __launch_bounds__(256) void cvtbf_kernel(CvtBfDesc d, const int* __restrict__ flags)
{
    const int fp32 = flags[0];
    const int seg = blockIdx.y;
    if (seg >= d.cnt) return;
    const long n = d.n[seg];
    const void* in = d.in[seg];
    bf16* out = d.out[seg];
    for (long i = (long)blockIdx.x * 256 + threadIdx.x; i < n; i += (long)gridDim.x * 256) {
        out[i] = fp32 ? __float2bfloat16(((const float*)in)[i])
                      : ((const bf16*)in)[i];
    }
}

// mask (int32 or int8 per flag) -> bf16 (1.0 where mask==0, else 0.0)
__global__ __launch_bounds__(256) void maskbf_kernel(
    const unsigned char* __restrict__ maskb, bf16* __restrict__ out,
    const int* __restrict__ flags)
{
    const int is32 = flags[1];
    for (long g = (long)blockIdx.x * 256 + threadIdx.x; g < (long)N_ * T_ * T_;
         g += (long)gridDim.x * 256) {
        const int v = is32 ? ((const int*)maskb)[g] : (int)maskb[g];
        out[g] = __float2bfloat16(v ? 0.f : 1.f);
    }
}

__global__ __launch_bounds__(256) void samp_kernel(const float* __restrict__ p, long n,
                                                   unsigned* __restrict__ slot)
{
    float m = 0.f;
    for (long i = (long)blockIdx.x * 256 + threadIdx.x; i < n; i += (long)gridDim.x * 256)
        m = fmaxf(m, fabsf(p[i]));
#pragma unroll
    for (int o = 32; o > 0; o >>= 1) m = fmaxf(m, __shfl_down(m, o, 64));
    if ((threadIdx.x & 63) == 0) atomicMax(slot, __float_as_uint(m));
}

__global__ void diag_kernel(float* __restrict__ out, const int* __restrict__ flags,
                            unsigned hostbad)
{
    if (threadIdx.x != 0 || blockIdx.x != 0) return;
    const unsigned* u = (const unsigned*)flags;
    float spike = 0.f;
    const float fm = __uint_as_float(u[8]);
    const float e1m = __uint_as_float(u[4]);
    const float s2m = __uint_as_float(u[5]);
    const float hm = __uint_as_float(u[6]);
    if (!(fm >= 0.05f && fm <= 50.f))   spike += 262144.f;     // bit18
    if (!(e1m >= 0.01f && e1m <= 1e4f)) spike += 524288.f;     // bit19
    if (flags[0] == 0)                  spike += 1048576.f;    // bit20
    if (!(s2m >= 1.f && s2m <= 1e6f))   spike += 8388608.f;    // bit23
    if (!(hm >= 2.f && hm <= 10.f))     spike += 16777216.f;   // bit24
    if (hostbad)                        spike += 33554432.f;   // bit25
    if (spike > 0.f) out[0] = spike;
}

__global__ void wsfail_kernel(float* __restrict__ out)
{
    if (threadIdx.x == 0 && blockIdx.x == 0) out[0] = 67108864.f;  // bit26
}

// ---------------------------------------------------------------------------
// MFMA bf16 GEMM: C[M,N] = A[M,K] @ B[N,K]^T + bias, opt ReLU. (r7-verified)
// ---------------------------------------------------------------------------
template <bool RELU, typename TC>
__global__ __launch_bounds__(256) void mfma_gemm(
    const bf16* __restrict__ A, const bf16* __restrict__ B,
    const float* __restrict__ bias, TC* __restrict__ C,
    int K, int N)
{
    __shared__ bf16 Asm[128][32];
    __shared__ bf16 Bsm[128][32];
    const int tid = threadIdx.x;
    const int lane = tid & 63;
    const int wave = tid >> 6;
    const int m16 = lane & 15;
    const int quad = lane >> 4;
    const long bm = (long)blockIdx.x * 128;
    const long bn = (long)blockIdx.y * 128;
    const int m_off = (wave >> 1) * 64;
    const int n_off = (wave & 1) * 64;

    f4v acc[4][4];
#pragma unroll
    for (int i = 0; i < 4; i++)
#pragma unroll
        for (int j = 0; j < 4; j++) acc[i][j] = (f4v){0.f, 0.f, 0.f, 0.f};

    for (int k0 = 0; k0 < K; k0 += 32) {
        __syncthreads();
#pragma unroll
        for (int rep = 0; rep < 2; rep++) {
            const int idx = rep * 256 + tid;
            const int row = idx >> 2;
            const int ck = (idx & 3) * 8;
            *(s8v*)&Asm[row][ck] = *(const s8v*)(A + (bm + row) * K + k0 + ck);
            *(s8v*)&Bsm[row][ck] = *(const s8v*)(B + (bn + row) * K + k0 + ck);
        }
        __syncthreads();
        s8v af[4], bfr[4];
#pragma unroll
        for (int t = 0; t < 4; t++) {
            af[t] = *(const s8v*)&Asm[m_off + t * 16 + m16][quad * 8];
            bfr[t] = *(const s8v*)&Bsm[n_off + t * 16 + m16][quad * 8];
        }
#pragma unroll
        for (int mt = 0; mt < 4; mt++)
#pragma unroll
            for (int nt = 0; nt < 4; nt++)
                acc[mt][nt] = __builtin_amdgcn_mfma_f32_16x16x32_bf16(
                    af[mt], bfr[nt], acc[mt][nt], 0, 0, 0);
    }

#pragma unroll
    for (int nt = 0; nt < 4; nt++) {
        const long col = bn + n_off + nt * 16 + m16;
        const float bv = bias ? bias[col] : 0.f;
#pragma unroll
        for (int mt = 0; mt < 4; mt++) {
            const long row0 = bm + m_off + mt * 16 + quad * 4;
#pragma unroll
            for (int r = 0; r < 4; r++) {
                float v = acc[mt][nt][r] + bv;
                if (RELU) v = fmaxf(v, 0.f);
                storeC(C + (row0 + r) * N + col, v);
            }
        }
    }
}

// ---------------------------------------------------------------------------
// Treat as MFMA: for fixed i, C[n][d] = sum_j maskbf[n,i,j] * E[(i+511-j),d].
// Block = (i, d-tile of 256). 4 waves, each d-subrange 64 (4x 16-tiles),
// both m-tiles (n 0..31). Per k-step: stage E1/E2 32-row slice transposed
// into LDS Bs[d 256][jj 32] (pad->40), frag-read aligned b128. A-frags
// direct from bf16 mask copy (16B aligned). Epilogue: *t1/t2, += into src2.
// ---------------------------------------------------------------------------
__global__ __launch_bounds__(256) void treat_mfma(
    const bf16* __restrict__ maskbf, const float* __restrict__ streat,
    const float* __restrict__ E1, const float* __restrict__ E2,
    float* __restrict__ src2)
{
    __shared__ bf16 Bs1[256][40];
    __shared__ bf16 Bs2[256][40];
    __shared__ float ts[64];
    const int i = blockIdx.x;
    const int d0 = blockIdx.y * 256;
    const int tid = threadIdx.x;
    const int lane = tid & 63, wave = tid >> 6;
    const int m16 = lane & 15, quad = lane >> 4;
    const int dwb = wave * 64;

    if (tid < 64) ts[tid] = streat[(long)(i * N_ + (tid >> 1)) * 2 + (tid & 1)];

    f4v acc1[2][4], acc2[2][4];
#pragma unroll
    for (int mt = 0; mt < 2; mt++)
#pragma unroll
        for (int ds = 0; ds < 4; ds++) {
            acc1[mt][ds] = (f4v){0.f, 0.f, 0.f, 0.f};
            acc2[mt][ds] = (f4v){0.f, 0.f, 0.f, 0.f};
        }

    for (int k0 = 0; k0 < 512; k0 += 32) {
        __syncthreads();
#pragma unroll
        for (int rep = 0; rep < 32; rep++) {
            const int idx = rep * 256 + tid;     // 0..8191
            const int jj = idx & 31;
            const int dl = idx >> 5;             // 0..255
            const long r = (long)(i + 511 - k0 - jj);
            Bs1[dl][jj] = __float2bfloat16(E1[r * 512 + d0 + dl]);
            Bs2[dl][jj] = __float2bfloat16(E2[r * 512 + d0 + dl]);
        }
        __syncthreads();
        s8v af[2], b1[4], b2[4];
#pragma unroll
        for (int mt = 0; mt < 2; mt++)
            af[mt] = *(const s8v*)(maskbf + (long)(mt * 16 + m16) * (T_ * T_)
                                   + (long)i * T_ + k0 + quad * 8);
#pragma unroll
        for (int ds = 0; ds < 4; ds++) {
            b1[ds] = *(const s8v*)&Bs1[dwb + ds * 16 + m16][quad * 8];
            b2[ds] = *(const s8v*)&Bs2[dwb + ds * 16 + m16][quad * 8];
        }
#pragma unroll
        for (int mt = 0; mt < 2; mt++)
#pragma unroll
            for (int ds = 0; ds < 4; ds++) {
                acc1[mt][ds] = __builtin_amdgcn_mfma_f32_16x16x32_bf16(
                    af[mt], b1[ds], acc1[mt][ds], 0, 0, 0);
                acc2[mt][ds] = __builtin_amdgcn_mfma_f32_16x16x32_bf16(
                    af[mt], b2[ds], acc2[mt][ds], 0, 0, 0);
            }
    }

#pragma unroll
    for (int mt = 0; mt < 2; mt++)
#pragma unroll
        for (int ds = 0; ds < 4; ds++) {
            const int d = d0 + dwb + ds * 16 + m16;
#pragma unroll
            for (int r = 0; r < 4; r++) {
                const int n = mt * 16 + quad * 4 + r;
                float* p = src2 + (long)i * (N_ * D_) + (long)n * D_ + d;
                *p += ts[n * 2] * acc1[mt][ds][r] + ts[n * 2 + 1] * acc2[mt][ds][r];
            }
        }
}

// ---------------------------------------------------------------------------
// VALU batched GEMM (attention QK/PV only).
// ---------------------------------------------------------------------------
template <typename TA, typename TB, typename TC, bool BT, bool RELU>
__global__ __launch_bounds__(256) void gemm_kernel(
    const TA* __restrict__ Ag, const TB* __restrict__ Bg,
    const float* __restrict__ bias, TC* __restrict__ Cg,
    int K, long lda, long ldb, long ldc,
    long a_sN, long a_sH, long b_sN, long b_sH,
    long c_sN, long c_sH, int Hdim, float alpha)
{
    __shared__ float As[16][68];
    __shared__ float Bs[16][68];
    const int tid = threadIdx.x;
    const int tx = tid & 15, ty = tid >> 4;
    const long bm = (long)blockIdx.x * 64;
    const long bn = (long)blockIdx.y * 64;
    const int z = blockIdx.z;
    const int zb = z / Hdim, zh = z % Hdim;
    const TA* A = Ag + zb * a_sN + zh * a_sH;
    const TB* B = Bg + zb * b_sN + zh * b_sH;
    TC* C = Cg + zb * c_sN + zh * c_sH;

    const int am = tid >> 2;
    const int ak = (tid & 3) << 2;

    float acc[4][4];
#pragma unroll
    for (int i = 0; i < 4; i++)
#pragma unroll
        for (int j = 0; j < 4; j++) acc[i][j] = 0.f;

    for (int k0 = 0; k0 < K; k0 += 16) {
        {
            float t4[4];
            load4(A + (bm + am) * lda + k0 + ak, t4);
#pragma unroll
            for (int i = 0; i < 4; i++) As[ak + i][am] = t4[i];
        }
        if constexpr (BT) {
            float t4[4];
            load4(B + (bn + am) * ldb + k0 + ak, t4);
#pragma unroll
            for (int i = 0; i < 4; i++) Bs[ak + i][am] = t4[i];
        } else {
            float t4[4];
            const int bk = tid >> 4;
            const int bc = (tid & 15) << 2;
            load4(B + (long)(k0 + bk) * ldb + bn + bc, t4);
#pragma unroll
            for (int i = 0; i < 4; i++) Bs[bk][bc + i] = t4[i];
        }
        __syncthreads();
#pragma unroll
        for (int kk = 0; kk < 16; kk++) {
            const float4 av = *reinterpret_cast<const float4*>(&As[kk][ty << 2]);
            const float4 bv = *reinterpret_cast<const float4*>(&Bs[kk][tx << 2]);
            const float a4[4] = {av.x, av.y, av.z, av.w};
            const float b4[4] = {bv.x, bv.y, bv.z, bv.w};
#pragma unroll
            for (int i = 0; i < 4; i++)
#pragma unroll
                for (int j = 0; j < 4; j++) acc[i][j] = fmaf(a4[i], b4[j], acc[i][j]);
        }
        __syncthreads();
    }
#pragma unroll
    for (int i = 0; i < 4; i++) {
        const long row = bm + (ty << 2) + i;
#pragma unroll
        for (int j = 0; j < 4; j++) {
            const long col = bn + (tx << 2) + j;
            float v = alpha * acc[i][j];
            if (bias) v += bias[col];
            if (RELU) v = fmaxf(v, 0.f);
            storeC(C + row * ldc + col, v);
        }
    }
}

// ---------------------------------------------------------------------------
__device__ __forceinline__ float blk_sum(float v) {
    __shared__ float sb[4];
#pragma unroll
    for (int o = 32; o > 0; o >>= 1) v += __shfl_down(v, o, 64);
    const int lane = threadIdx.x & 63, w = threadIdx.x >> 6;
    if (lane == 0) sb[w] = v;
    __syncthreads();
    v = sb[0] + sb[1] + sb[2] + sb[3];
    __syncthreads();
    return v;
}
__device__ __forceinline__ float blk_max(float v) {
    __shared__ float sm[4];
#pragma unroll
    for (int o = 32; o > 0; o >>= 1) v = fmaxf(v, __shfl_down(v, o, 64));
    const int lane = threadIdx.x & 63, w = threadIdx.x >> 6;
    if (lane == 0) sm[w] = v;
    __syncthreads();
    v = fmaxf(fmaxf(sm[0], sm[1]), fmaxf(sm[2], sm[3]));
    __syncthreads();
    return v;
}

__global__ __launch_bounds__(256) void softmax_kernel(bf16* __restrict__ S)
{
    bf16* row = S + (long)blockIdx.x * 512;
    const int tid = threadIdx.x;
    const float v0 = tofl(row[tid]);
    const float v1 = tofl(row[tid + 256]);
    const float m = blk_max(fmaxf(v0, v1));
    const float e0 = __expf(v0 - m);
    const float e1 = __expf(v1 - m);
    const float s = blk_sum(e0 + e1);
    const float inv = 1.f / s;
    row[tid] = __float2bfloat16(e0 * inv);
    row[tid + 256] = __float2bfloat16(e1 * inv);
}

template <typename TIN>
__global__ __launch_bounds__(256) void ln_kernel(
    const TIN* __restrict__ X, const float* __restrict__ Add,
    const float* __restrict__ g, const float* __restrict__ b,
    float* __restrict__ out, bf16* __restrict__ out_bf)
{
    const long base = (long)blockIdx.x * 512;
    const int tid = threadIdx.x;
    const float x0 = tofl(X[base + tid]) + Add[base + tid];
    const float x1 = tofl(X[base + tid + 256]) + Add[base + tid + 256];
    const float mean = blk_sum(x0 + x1) * (1.f / 512.f);
    const float d0 = x0 - mean, d1 = x1 - mean;
    const float var = blk_sum(d0 * d0 + d1 * d1) * (1.f / 512.f);
    const float inv = rsqrtf(var + EPS_);
    const float v0 = d0 * inv * g[tid] + b[tid];
    const float v1 = d1 * inv * g[tid + 256] + b[tid + 256];
    out[base + tid] = v0;
    out[base + tid + 256] = v1;
    if (out_bf) {
        out_bf[base + tid] = __float2bfloat16(v0);
        out_bf[base + tid + 256] = __float2bfloat16(v1);
    }
}

__global__ __launch_bounds__(256) void etable_kernel(
    const float* __restrict__ w1, const float* __restrict__ b1,
    const float* __restrict__ w2, const float* __restrict__ b2,
    float* __restrict__ E)
{
    __shared__ float hid[MH_];
    const int r = blockIdx.x;
    const float td = (float)(r - 511);
    const int tid = threadIdx.x;
    if (tid < MH_) hid[tid] = fmaxf(fmaf(td, w1[tid], b1[tid]), 0.f);
    __syncthreads();
#pragma unroll
    for (int rep = 0; rep < 2; rep++) {
        const int d = tid + rep * 256;
        float acc = b2[d];
        for (int m = 0; m < MH_; m++) acc = fmaf(w2[d * MH_ + m], hid[m], acc);
        E[(long)r * 512 + d] = acc;
    }
}

// ---------------------------------------------------------------------------
extern "C" void kernel_launch(void* const* d_in, const int* in_sizes, int n_in,
                              void* d_out, int out_size, void* d_ws, size_t ws_size,
                              hipStream_t stream)
{
    const unsigned char* mtreat = (const unsigned char*)d_in[3];
    float* out = (float*)d_out;

    static const int expect[26] = {8388608, 32768, 8388608, 8388608, 262144, 512,
                                   786432, 1536, 262144, 512, 50, 50, 25600, 512,
                                   50, 50, 25600, 512, 1048576, 2048, 1048576, 512,
                                   512, 512, 512, 512};
    unsigned hostbad = 0;
    if (n_in != 26 || out_size != 8388608) hostbad = 1;
    else
        for (int i = 0; i < 26; i++)
            if (in_sizes[i] != expect[i]) hostbad = 1;

    // --- workspace layout (bytes), phase-overlapped ---
    char* w = (char*)d_ws;
    const size_t OFF_SRCF  = 0;           // src fp32 -> ff fp32 later
    const size_t OFF_SRC2  = 33554432;    // src2 fp32
    const size_t OFF_E1    = 67108864;
    const size_t OFF_E2    = OFF_E1 + 2095104;
    const size_t OFF_WBF   = OFF_E2 + 2095104;
    const size_t OFF_WF    = OFF_WBF + 6815744;
    const size_t OFF_FLAGS = OFF_WF + 369440;
    const size_t OFF_XBF   = 79691776;    // x_bf -> o_bf later
    const size_t OFF_QKV   = 100663296;   // qkvb bf16 / h fp32 later
    const size_t OFF_H     = 100663296;
    const size_t OFF_FF1   = 134217728;   // ff1b chunks (post-attn)
    const size_t OFF_SB    = 150994944;   // Sb bf16 (attn only)
    const size_t OFF_SRCBF = 167772160;   // src_bf -> h_bf later
    const size_t OFF_MASKBF= 184549376;   // mask bf16 (16.8 MB, treat only)
    const size_t NEED      = OFF_MASKBF + 16777216;  // 201326592 < 205516864 proven
    if (ws_size < NEED) {
        wsfail_kernel<<<1, 64, 0, stream>>>(out);
        return;
    }

    float* src_f = (float*)(w + OFF_SRCF);
    float* ff    = (float*)(w + OFF_SRCF);
    float* src2  = (float*)(w + OFF_SRC2);
    float* E1    = (float*)(w + OFF_E1);
    float* E2    = (float*)(w + OFF_E2);
    bf16*  x_bf  = (bf16*)(w + OFF_XBF);
    bf16*  o_bf  = (bf16*)(w + OFF_XBF);
    bf16*  qkvb  = (bf16*)(w + OFF_QKV);
    float* h     = (float*)(w + OFF_H);
    bf16*  ff1b  = (bf16*)(w + OFF_FF1);
    bf16*  Sb    = (bf16*)(w + OFF_SB);
    bf16*  src_bf= (bf16*)(w + OFF_SRCBF);
    bf16*  h_bf  = (bf16*)(w + OFF_SRCBF);
    bf16*  maskbf= (bf16*)(w + OFF_MASKBF);
    int*   flags = (int*)(w + OFF_FLAGS);
    unsigned* stats = (unsigned*)flags;

    bf16* Wmap_bf = (bf16*)(w + OFF_WBF);
    bf16* Wqkv_bf = Wmap_bf + 262144;
    bf16* Wo_bf   = Wqkv_bf + 786432;
    bf16* W1_bf   = Wo_bf + 262144;
    bf16* W2_bf   = W1_bf + 1048576;

    probe_kernel<<<1, 256, 0, stream>>>(
        (const unsigned short*)d_in[0], mtreat, flags);

    CvtDesc cd{};
    float* wfp[26] = {nullptr};
    int k = 0;
    auto add = [&](int idx, float* dst) {
        cd.in[k] = d_in[idx]; cd.out[k] = dst; cd.n[k] = in_sizes[idx];
        wfp[idx] = dst; k++;
    };
    add(0, src_f);
    {
        float* p = (float*)(w + OFF_WF);
        const int idxs[18] = {1, 5, 7, 9, 10, 11, 12, 13, 14, 15, 16, 17,
                              19, 21, 22, 23, 24, 25};
        for (int q = 0; q < 18; q++) { add(idxs[q], p); p += in_sizes[idxs[q]]; }
    }
    cd.cnt = k;  // 19
    cvt_kernel<<<dim3(512, 19), 256, 0, stream>>>(cd, flags);

    CvtBfDesc cb{};
    cb.in[0] = d_in[0];  cb.out[0] = src_bf;  cb.n[0] = in_sizes[0];
    cb.in[1] = d_in[4];  cb.out[1] = Wmap_bf; cb.n[1] = in_sizes[4];
    cb.in[2] = d_in[6];  cb.out[2] = Wqkv_bf; cb.n[2] = in_sizes[6];
    cb.in[3] = d_in[8];  cb.out[3] = Wo_bf;   cb.n[3] = in_sizes[8];
    cb.in[4] = d_in[18]; cb.out[4] = W1_bf;   cb.n[4] = in_sizes[18];
    cb.in[5] = d_in[20]; cb.out[5] = W2_bf;   cb.n[5] = in_sizes[20];
    cb.cnt = 6;
    cvtbf_kernel<<<dim3(512, 6), 256, 0, stream>>>(cb, flags);

    // mask -> bf16 (for treat MFMA A-operand)
    maskbf_kernel<<<8192, 256, 0, stream>>>(mtreat, maskbf, flags);

    const float* streat_f = wfp[1];
    const float* b_map = wfp[5], *bqkv = wfp[7], *bo = wfp[9];
    const float* m1w1 = wfp[10], *m1b1 = wfp[11], *m1w2 = wfp[12], *m1b2 = wfp[13];
    const float* m2w1 = wfp[14], *m2b1 = wfp[15], *m2w2 = wfp[16], *m2b2 = wfp[17];
    const float* b1 = wfp[19], *b2 = wfp[21];
    const float* ln1g = wfp[22], *ln1b = wfp[23], *ln2g = wfp[24], *ln2b = wfp[25];

    etable_kernel<<<1023, 256, 0, stream>>>(m1w1, m1b1, m1w2, m1b2, E1);
    etable_kernel<<<1023, 256, 0, stream>>>(m2w1, m2b1, m2w2, m2b2, E2);
    samp_kernel<<<256, 256, 0, stream>>>(E1, 523776, &stats[4]);

    mfma_gemm<false, bf16><<<dim3(128, 4), 256, 0, stream>>>(
        src_bf, Wmap_bf, b_map, x_bf, 512, 512);
    mfma_gemm<false, bf16><<<dim3(128, 12), 256, 0, stream>>>(
        x_bf, Wqkv_bf, bqkv, qkvb, 512, 1536);

    for (int c = 0; c < 8; c++) {
        const long n0 = (long)c * 4;
        gemm_kernel<bf16, bf16, bf16, true, false><<<dim3(8, 8, 32), 256, 0, stream>>>(
            qkvb + n0 * 1536, qkvb + n0 * 1536 + 512, nullptr, Sb,
            64, 49152, 49152, 512,
            1536, 64, 1536, 64, 2097152, 262144, 8, 0.125f);
        softmax_kernel<<<16384, 256, 0, stream>>>(Sb);
        gemm_kernel<bf16, bf16, bf16, false, false><<<dim3(8, 1, 32), 256, 0, stream>>>(
            Sb, qkvb + n0 * 1536 + 1024, nullptr, o_bf + n0 * 512,
            512, 512, 49152, 16384,
            2097152, 262144, 1536, 64, 512, 64, 8, 1.f);
    }

    mfma_gemm<false, float><<<dim3(128, 4), 256, 0, stream>>>(
        o_bf, Wo_bf, bo, src2, 512, 512);
    // treat: MFMA GEMM per (i, d-tile)
    treat_mfma<<<dim3(512, 2), 256, 0, stream>>>(
        maskbf, streat_f, E1, E2, src2);
    samp_kernel<<<512, 256, 0, stream>>>(src2, 8388608, &stats[5]);

    ln_kernel<float><<<16384, 256, 0, stream>>>(src_f, src2, ln1g, ln1b, h, h_bf);
    samp_kernel<<<512, 256, 0, stream>>>(h, 8388608, &stats[6]);

    for (int c = 0; c < 2; c++) {
        const long r0 = (long)c * 8192;
        mfma_gemm<true, bf16><<<dim3(64, 16), 256, 0, stream>>>(
            h_bf + r0 * 512, W1_bf, b1, ff1b, 512, 2048);
        mfma_gemm<false, float><<<dim3(64, 4), 256, 0, stream>>>(
            ff1b, W2_bf, b2, ff + r0 * 512, 2048, 512);
    }
    samp_kernel<<<512, 256, 0, stream>>>(ff, 8388608, &stats[8]);

    ln_kernel<float><<<16384, 256, 0, stream>>>(h, ff, ln2g, ln2b, out, nullptr);
    diag_kernel<<<1, 64, 0, stream>>>(out, flags, hostbad);
}